// Round 8
// baseline (407.997 us; speedup 1.0000x reference)
//
#include <hip/hip_runtime.h>
#include <hip/hip_bf16.h>

// Problem constants (from setup_inputs: x = [2, 1024, 64] fp32)
constexpr int BB = 2;
constexpr int N  = 1024;
constexpr int C  = 64;
constexpr int S  = N * N;          // 1048576 = 2^20
constexpr int KSEL = S / 6;        // 174762 entries set to 1 per batch
constexpr int EQCAP   = 1 << 19;   // tie-pair capacity per batch
constexpr int NSELBLK = 256;       // select grid == #CUs -> co-resident

typedef double d4 __attribute__((ext_vector_type(4)));

// Order-preserving uint64 mapping of fp64 (monotone: a<b <=> key(a)<key(b))
__device__ __forceinline__ unsigned long long d2key(double d) {
    unsigned long long u = (unsigned long long)__double_as_longlong(d);
    return (u & 0x8000000000000000ULL) ? ~u : (u | 0x8000000000000000ULL);
}

// Agent-scope primitives. Loads are plain cache-bypassing loads (parallel at
// the coherence point); RMWs reserved for actual read-modify-write needs.
__device__ __forceinline__ unsigned int aload(const unsigned int* p) {
    return __hip_atomic_load(p, __ATOMIC_RELAXED, __HIP_MEMORY_SCOPE_AGENT);
}
__device__ __forceinline__ void astore(unsigned int* p, unsigned int v) {
    (void)__hip_atomic_exchange(p, v, __ATOMIC_RELAXED, __HIP_MEMORY_SCOPE_AGENT);
}

// ---------------------------------------------------------------------------
// K1: pairwise adjacencies with fused per-row stats. 64x64 tile (512 wgs).
__global__ __launch_bounds__(256) void k_pairwise(const float* __restrict__ x,
                                                  double* __restrict__ E,
                                                  double* __restrict__ Ch,
                                                  double* __restrict__ Cc) {
    int b  = blockIdx.z;
    int i0 = blockIdx.y * 64;
    int j0 = blockIdx.x * 64;
    __shared__ double xi[64][65];
    __shared__ double xj[64][65];
    __shared__ double mi[64], ri_[64], si[64];
    __shared__ double mj[64], rj_[64], sj[64];

    int t  = threadIdx.x;
    int r  = t >> 2;
    int cb = (t & 3) * 16;
    const float* xb = x + (size_t)b * N * C;
    {
        const float4* pi = (const float4*)(xb + (size_t)(i0 + r) * C + cb);
        const float4* pj = (const float4*)(xb + (size_t)(j0 + r) * C + cb);
#pragma unroll
        for (int m4 = 0; m4 < 4; ++m4) {
            float4 fi = pi[m4], fj = pj[m4];
            xi[r][cb + 4 * m4 + 0] = (double)fi.x; xi[r][cb + 4 * m4 + 1] = (double)fi.y;
            xi[r][cb + 4 * m4 + 2] = (double)fi.z; xi[r][cb + 4 * m4 + 3] = (double)fi.w;
            xj[r][cb + 4 * m4 + 0] = (double)fj.x; xj[r][cb + 4 * m4 + 1] = (double)fj.y;
            xj[r][cb + 4 * m4 + 2] = (double)fj.z; xj[r][cb + 4 * m4 + 3] = (double)fj.w;
        }
    }
    __syncthreads();

    if (t < 128) {
        int row = t & 63;
        const double (*xs)[65] = (t < 64) ? xi : xj;
        double sum = 0.0, rr = 0.0;
#pragma unroll 8
        for (int c = 0; c < 64; ++c) { double v = xs[row][c]; sum += v; rr = fma(v, v, rr); }
        double m = sum / 64.0;
        double q = 0.0;
#pragma unroll 8
        for (int c = 0; c < 64; ++c) { double w = xs[row][c] - m; q = fma(w, w, q); }
        double sv = 1.0 / sqrt(q);
        if (t < 64) { mi[row] = m; ri_[row] = rr; si[row] = sv; }
        else        { mj[row] = m; rj_[row] = rr; sj[row] = sv; }
    }
    __syncthreads();

    int ty = t >> 4, tx = t & 15;
    double adot[4][4] = {};
    double amax[4][4] = {};
#pragma unroll 8
    for (int c = 0; c < 64; ++c) {
        double ai[4], aj[4];
#pragma unroll
        for (int p = 0; p < 4; ++p) ai[p] = xi[ty + 16 * p][c];
#pragma unroll
        for (int q = 0; q < 4; ++q) aj[q] = xj[tx + 16 * q][c];
#pragma unroll
        for (int p = 0; p < 4; ++p)
#pragma unroll
            for (int q = 0; q < 4; ++q) {
                double d = ai[p] - aj[q];
                amax[p][q] = fmax(amax[p][q], fabs(d));
                adot[p][q] = fma(ai[p], aj[q], adot[p][q]);
            }
    }

#pragma unroll
    for (int p = 0; p < 4; ++p) {
        int li = ty + 16 * p;
        int ii = i0 + li;
        double rri = ri_[li], mmi = mi[li], ssi = si[li];
#pragma unroll
        for (int q = 0; q < 4; ++q) {
            int lj = tx + 16 * q;
            int jj = j0 + lj;
            double dot = adot[p][q];
            double d2  = rri + rj_[lj] - 2.0 * dot;
            double e   = (ii == jj) ? 0.0 : sqrt(fmax(d2, 0.0));
            double cc  = (dot - 64.0 * mmi * mj[lj]) * ssi * sj[lj];
            cc = fmin(1.0, fmax(-1.0, cc));
            size_t idx = (size_t)b * S + (size_t)ii * N + jj;
            E[idx]  = e;
            Ch[idx] = amax[p][q];
            Cc[idx] = cc;
        }
    }
}

// ---------------------------------------------------------------------------
// K2: C = scale * A * B^T (fp64, MFMA). 64x64 tile, 4 waves x 32x32 quadrant,
// LDS double-buffered, BK=32.
__global__ __launch_bounds__(256) void k_gemm_nt(const double* __restrict__ A,
                                                 const double* __restrict__ Bm,
                                                 double* __restrict__ Cm,
                                                 double scale) {
    int b = blockIdx.z;
    const double* Ab = A  + (size_t)b * S;
    const double* Bb = Bm + (size_t)b * S;
    double*       Cb = Cm + (size_t)b * S;
    int i0 = blockIdx.y * 64, j0 = blockIdx.x * 64;

    __shared__ double At[2][64][33];
    __shared__ double Bt[2][64][33];

    int t    = threadIdx.x;
    int lane = t & 63;
    int w    = t >> 6;
    int wr   = (w >> 1) * 32;
    int wc   = (w & 1) * 32;
    int fm   = lane & 15;
    int fk   = lane >> 4;

    int sr = t >> 2, sc0 = (t & 3) * 8;

    d4 acc00 = {0.0, 0.0, 0.0, 0.0};
    d4 acc01 = acc00, acc10 = acc00, acc11 = acc00;

    const double* ap = Ab + (size_t)(i0 + sr) * N + sc0;
    const double* bp = Bb + (size_t)(j0 + sr) * N + sc0;

    double pa[8], pb[8];
#pragma unroll
    for (int m = 0; m < 8; ++m) { pa[m] = ap[m]; pb[m] = bp[m]; }
#pragma unroll
    for (int m = 0; m < 8; ++m) { At[0][sr][sc0 + m] = pa[m]; Bt[0][sr][sc0 + m] = pb[m]; }
    __syncthreads();

    int cur = 0;
    for (int k0 = 0; k0 < N; k0 += 32) {
        bool has_next = (k0 + 32 < N);
        if (has_next) {
            ap += 32; bp += 32;
#pragma unroll
            for (int m = 0; m < 8; ++m) { pa[m] = ap[m]; pb[m] = bp[m]; }
        }
#pragma unroll
        for (int kq = 0; kq < 8; ++kq) {
            int kk = kq * 4 + fk;
            double a0 = At[cur][wr + fm][kk];
            double a1 = At[cur][wr + 16 + fm][kk];
            double b0 = Bt[cur][wc + fm][kk];
            double b1 = Bt[cur][wc + 16 + fm][kk];
            acc00 = __builtin_amdgcn_mfma_f64_16x16x4f64(a0, b0, acc00, 0, 0, 0);
            acc01 = __builtin_amdgcn_mfma_f64_16x16x4f64(a0, b1, acc01, 0, 0, 0);
            acc10 = __builtin_amdgcn_mfma_f64_16x16x4f64(a1, b0, acc10, 0, 0, 0);
            acc11 = __builtin_amdgcn_mfma_f64_16x16x4f64(a1, b1, acc11, 0, 0, 0);
        }
        if (has_next) {
            int nxt = cur ^ 1;
#pragma unroll
            for (int m = 0; m < 8; ++m) { At[nxt][sr][sc0 + m] = pa[m]; Bt[nxt][sr][sc0 + m] = pb[m]; }
            __syncthreads();
            cur = nxt;
        }
    }
    int r0 = i0 + wr + 4 * fk;
    int c0 = j0 + wc + fm;
#pragma unroll
    for (int r = 0; r < 4; ++r) {
        Cb[(size_t)(r0 + r)      * N + c0]      = acc00[r] * scale;
        Cb[(size_t)(r0 + r)      * N + c0 + 16] = acc01[r] * scale;
        Cb[(size_t)(r0 + 16 + r) * N + c0]      = acc10[r] * scale;
        Cb[(size_t)(r0 + 16 + r) * N + c0 + 16] = acc11[r] * scale;
    }
}

// ---------------------------------------------------------------------------
// K4: W = A * B (fp64, MFMA) + key32 epilogue. Block (0,0,0) zeroes all of
// k_select's scratch (bar lines, hist, eq counters) via plain stores — the
// kernel-end release flush makes them visible & clean device-wide.
__global__ __launch_bounds__(256) void k_gemm_nn(const double* __restrict__ A,
                                                 const double* __restrict__ Bm,
                                                 double* __restrict__ Wm,
                                                 unsigned int* __restrict__ kq_out,
                                                 unsigned int* __restrict__ bar,
                                                 int* __restrict__ hist,
                                                 unsigned int* __restrict__ eqcnt) {
    if (blockIdx.x == 0 && blockIdx.y == 0 && blockIdx.z == 0) {
        int tt = threadIdx.x;
        if (tt < 32) bar[tt] = 0u;          // arrival ctr line + release line
        for (int i = tt; i < 2048; i += 256) hist[i] = 0;
        if (tt < BB) eqcnt[tt * 16] = 0u;   // one line per batch
    }

    int b = blockIdx.z;
    const double* Ab = A  + (size_t)b * S;
    const double* Bb = Bm + (size_t)b * S;
    double*       Wb = Wm + (size_t)b * S;
    unsigned int* kb = kq_out + (size_t)b * S;
    int i0 = blockIdx.y * 64, j0 = blockIdx.x * 64;

    __shared__ double At[2][64][33];
    __shared__ double Bt[2][32][65];

    int t    = threadIdx.x;
    int lane = t & 63;
    int w    = t >> 6;
    int wr   = (w >> 1) * 32;
    int wc   = (w & 1) * 32;
    int fm   = lane & 15;
    int fk   = lane >> 4;

    int sr = t >> 2, sc0 = (t & 3) * 8;   // A staging: 64 rows x 32 k
    int br = t >> 3, bc = (t & 7) * 8;    // B staging: 32 k x 64 cols

    d4 acc00 = {0.0, 0.0, 0.0, 0.0};
    d4 acc01 = acc00, acc10 = acc00, acc11 = acc00;

    const double* ap = Ab + (size_t)(i0 + sr) * N + sc0;
    const double* bp = Bb + (size_t)br * N + j0 + bc;

    double pa[8], pb[8];
#pragma unroll
    for (int m = 0; m < 8; ++m) { pa[m] = ap[m]; pb[m] = bp[m]; }
#pragma unroll
    for (int m = 0; m < 8; ++m) { At[0][sr][sc0 + m] = pa[m]; Bt[0][br][bc + m] = pb[m]; }
    __syncthreads();

    int cur = 0;
    for (int k0 = 0; k0 < N; k0 += 32) {
        bool has_next = (k0 + 32 < N);
        if (has_next) {
            ap += 32; bp += (size_t)32 * N;
#pragma unroll
            for (int m = 0; m < 8; ++m) { pa[m] = ap[m]; pb[m] = bp[m]; }
        }
#pragma unroll
        for (int kq = 0; kq < 8; ++kq) {
            int kk = kq * 4 + fk;
            double a0 = At[cur][wr + fm][kk];
            double a1 = At[cur][wr + 16 + fm][kk];
            double b0 = Bt[cur][kk][wc + fm];
            double b1 = Bt[cur][kk][wc + 16 + fm];
            acc00 = __builtin_amdgcn_mfma_f64_16x16x4f64(a0, b0, acc00, 0, 0, 0);
            acc01 = __builtin_amdgcn_mfma_f64_16x16x4f64(a0, b1, acc01, 0, 0, 0);
            acc10 = __builtin_amdgcn_mfma_f64_16x16x4f64(a1, b0, acc10, 0, 0, 0);
            acc11 = __builtin_amdgcn_mfma_f64_16x16x4f64(a1, b1, acc11, 0, 0, 0);
        }
        if (has_next) {
            int nxt = cur ^ 1;
#pragma unroll
            for (int m = 0; m < 8; ++m) { At[nxt][sr][sc0 + m] = pa[m]; Bt[nxt][br][bc + m] = pb[m]; }
            __syncthreads();
            cur = nxt;
        }
    }
    int r0 = i0 + wr + 4 * fk;
    int c0 = j0 + wc + fm;
#pragma unroll
    for (int r = 0; r < 4; ++r) {
        double w00 = acc00[r], w01 = acc01[r], w10 = acc10[r], w11 = acc11[r];
        size_t i00 = (size_t)(r0 + r)      * N + c0;
        size_t i01 = (size_t)(r0 + r)      * N + c0 + 16;
        size_t i10 = (size_t)(r0 + 16 + r) * N + c0;
        size_t i11 = (size_t)(r0 + 16 + r) * N + c0 + 16;
        Wb[i00] = w00; kb[i00] = (unsigned int)(d2key(w00) >> 32);
        Wb[i01] = w01; kb[i01] = (unsigned int)(d2key(w01) >> 32);
        Wb[i10] = w10; kb[i10] = (unsigned int)(d2key(w10) >> 32);
        Wb[i11] = w11; kb[i11] = (unsigned int)(d2key(w11) >> 32);
    }
}

// ---------------------------------------------------------------------------
// K3: fp64 row softmax. Wave per row, shuffle-only; 512 wgs.
__global__ __launch_bounds__(256) void k_softmax(double* __restrict__ L) {
    int row = (blockIdx.x << 2) + (threadIdx.x >> 6);
    int ln  = threadIdx.x & 63;
    double* p = L + (size_t)row * N;

    double v[16];
#pragma unroll
    for (int q = 0; q < 16; ++q) v[q] = p[ln + 64 * q];

    double mx = v[0];
#pragma unroll
    for (int q = 1; q < 16; ++q) mx = fmax(mx, v[q]);
#pragma unroll
    for (int off = 32; off >= 1; off >>= 1) mx = fmax(mx, __shfl_xor(mx, off));

    double s = 0.0;
#pragma unroll
    for (int q = 0; q < 16; ++q) { v[q] = exp(v[q] - mx); s += v[q]; }
#pragma unroll
    for (int off = 32; off >= 1; off >>= 1) s += __shfl_xor(s, off);

#pragma unroll
    for (int q = 0; q < 16; ++q) p[ln + 64 * q] = v[q] / s;
}

// ---------------------------------------------------------------------------
// K5: fused selection. 256 co-resident blocks, 6 grid barriers.
// Barrier: one arrival RMW per block + release flag on its OWN cache line;
// spinners poll with agent-scope atomic_load (no RMW -> no coherence-point
// queue saturation). All cross-block reads are atomic_loads, not fetch_adds.
__device__ __forceinline__ void gridbar(unsigned int* bar, unsigned int* phase) {
    __syncthreads();
    if (threadIdx.x == 0) {
        asm volatile("s_waitcnt vmcnt(0)" ::: "memory");
        unsigned int ph  = ++(*phase);
        unsigned int arr = __hip_atomic_fetch_add(&bar[0], 1u, __ATOMIC_RELAXED,
                                                  __HIP_MEMORY_SCOPE_AGENT) + 1u;
        if (arr == ph * (unsigned int)NSELBLK) {
            astore(&bar[16], ph);             // release (separate 64B line)
        } else {
            while (aload(&bar[16]) < ph) __builtin_amdgcn_s_sleep(2);
        }
        asm volatile("" ::: "memory");
    }
    __syncthreads();
}

__global__ __launch_bounds__(256) void k_select(const unsigned int* __restrict__ key32,
                                                const double* __restrict__ W,
                                                int* __restrict__ hist,      // 4*2*256 ints
                                                unsigned int* __restrict__ eqcnt,
                                                unsigned long long* __restrict__ eqpairs,
                                                unsigned int* __restrict__ sc,
                                                unsigned int* __restrict__ bar,
                                                float* __restrict__ out) {
    int blk = blockIdx.x, t = threadIdx.x;
    int b  = blk >> 7;            // 128 blocks per batch
    int lb = blk & 127;
    int lane = t & 63;
    unsigned int phase = 0;

    __shared__ int lh[256];
    __shared__ unsigned int s_pref, s_kneed;

    const uint4* k4 = (const uint4*)(key32 + (size_t)b * S);
    unsigned int pref = 0, kneed = (unsigned int)KSEL;

    // ---- 4 radix passes on key32 (scratch pre-zeroed by k_gemm_nn) ----
    for (int p = 0; p < 4; ++p) {
        int shift = 24 - 8 * p;
        lh[t] = 0;
        __syncthreads();
        unsigned int prefh = (p == 0) ? 0u : (pref >> (shift + 8));
        for (int it = 0; it < 8; ++it) {
            int g4 = (it * 128 + lb) * 256 + t;
            uint4 kv = k4[g4];
            unsigned int ks[4] = {kv.x, kv.y, kv.z, kv.w};
#pragma unroll
            for (int c = 0; c < 4; ++c) {
                bool match = (p == 0) || ((ks[c] >> (shift + 8)) == prefh);
                if (match) atomicAdd(&lh[(ks[c] >> shift) & 255u], 1);
            }
        }
        __syncthreads();
        if (lh[t] != 0)
            __hip_atomic_fetch_add((unsigned int*)&hist[(p * 2 + b) * 256 + t],
                                   (unsigned int)lh[t], __ATOMIC_RELAXED,
                                   __HIP_MEMORY_SCOPE_AGENT);
        gridbar(bar, &phase);
        lh[t] = (int)aload((const unsigned int*)&hist[(p * 2 + b) * 256 + t]);
        __syncthreads();
        if (t == 0) {
            unsigned int cum = 0; int bucket = 0;
            for (int i = 255; i >= 0; --i) {
                unsigned int h = (unsigned int)lh[i];
                if (cum + h >= kneed) { bucket = i; break; }
                cum += h;
            }
            s_pref  = pref | ((unsigned int)bucket << shift);
            s_kneed = kneed - cum;
        }
        __syncthreads();
        pref = s_pref; kneed = s_kneed;
        __syncthreads();
    }

    // ---- eq-collect: wave-ballot aggregated counter, 64-bit pair writes ----
    unsigned int* ecnt = &eqcnt[b * 16];
    unsigned long long* epair = eqpairs + (size_t)b * EQCAP;
    unsigned long long lmask = (lane == 63) ? ~0ULL : ((1ULL << (lane + 1)) - 1ULL);
    lmask >>= 1;  // bits below this lane... (1ULL<<lane)-1, lane=63-safe
    for (int it = 0; it < 8; ++it) {
        int g4 = (it * 128 + lb) * 256 + t;
        uint4 kv = k4[g4];
        unsigned int ks[4] = {kv.x, kv.y, kv.z, kv.w};
#pragma unroll
        for (int c = 0; c < 4; ++c) {
            bool m = (ks[c] == pref);
            unsigned long long mb = __ballot(m);
            if (mb == 0ULL) continue;
            int ldr = __ffsll((long long)mb) - 1;
            unsigned int base = 0;
            if (lane == ldr)
                base = __hip_atomic_fetch_add(ecnt, (unsigned int)__popcll(mb),
                                              __ATOMIC_RELAXED, __HIP_MEMORY_SCOPE_AGENT);
            base = __shfl(base, ldr, 64);
            if (m) {
                unsigned int pos = base + (unsigned int)__popcll(mb & lmask);
                if (pos < (unsigned int)EQCAP) {
                    int s = g4 * 4 + c;
                    unsigned int low = (unsigned int)d2key(W[(size_t)b * S + s]);
                    unsigned long long pr = ((unsigned long long)(unsigned int)s << 32) | low;
                    (void)__hip_atomic_exchange(&epair[pos], pr, __ATOMIC_RELAXED,
                                                __HIP_MEMORY_SCOPE_AGENT);
                }
            }
        }
    }
    gridbar(bar, &phase);

    // ---- refine (one block per batch): 4 passes low32 + 3 passes idx ----
    if (lb == 0) {
        unsigned int cnt = aload(ecnt);
        if (cnt > (unsigned int)EQCAP) cnt = EQCAP;
        unsigned int rpref = 0, rkneed = kneed;
        for (int shift = 24; shift >= 0; shift -= 8) {
            lh[t] = 0;
            __syncthreads();
            unsigned int ph = (shift == 24) ? 0u : (rpref >> (shift + 8));
            for (unsigned int e = t; e < cnt; e += 256) {
                unsigned int low = (unsigned int)epair[e];   // plain load: lines only
                bool match = (shift == 24) || ((low >> (shift + 8)) == ph); // RMW-written
                if (match) atomicAdd(&lh[(low >> shift) & 255u], 1);
            }
            __syncthreads();
            if (t == 0) {
                unsigned int cum = 0; int bucket = 0;
                for (int i = 255; i >= 0; --i) {
                    unsigned int h = (unsigned int)lh[i];
                    if (cum + h >= rkneed) { bucket = i; break; }
                    cum += h;
                }
                s_pref  = rpref | ((unsigned int)bucket << shift);
                s_kneed = rkneed - cum;
            }
            __syncthreads();
            rpref = s_pref; rkneed = s_kneed;
            __syncthreads();
        }
        unsigned int TL = rpref;
        unsigned int ipref = 0;
        for (int shift = 16; shift >= 0; shift -= 8) {
            lh[t] = 0;
            __syncthreads();
            unsigned int ph = (shift == 16) ? 0u : (ipref >> (shift + 8));
            for (unsigned int e = t; e < cnt; e += 256) {
                unsigned long long pr = epair[e];
                unsigned int low = (unsigned int)pr;
                if (low != TL) continue;
                unsigned int idx = (unsigned int)(pr >> 32);
                bool match = (shift == 16) || ((idx >> (shift + 8)) == ph);
                if (match) atomicAdd(&lh[(idx >> shift) & 255u], 1);
            }
            __syncthreads();
            if (t == 0) {
                unsigned int cum = 0; int bucket = 0;
                for (int i = 255; i >= 0; --i) {
                    unsigned int h = (unsigned int)lh[i];
                    if (cum + h >= rkneed) { bucket = i; break; }
                    cum += h;
                }
                s_pref  = ipref | ((unsigned int)bucket << shift);
                s_kneed = rkneed - cum;
            }
            __syncthreads();
            ipref = s_pref; rkneed = s_kneed;
            __syncthreads();
        }
        if (t == 0) { astore(&sc[2 * b], TL); astore(&sc[2 * b + 1], ipref); }
    }
    gridbar(bar, &phase);

    // ---- final mask ----
    unsigned int TL   = aload(&sc[2 * b]);
    unsigned int sCut = aload(&sc[2 * b + 1]);
    float4* out4 = (float4*)(out + (size_t)b * S);
    for (int it = 0; it < 8; ++it) {
        int g4 = (it * 128 + lb) * 256 + t;
        uint4 kv = k4[g4];
        unsigned int ks[4] = {kv.x, kv.y, kv.z, kv.w};
        float ov[4];
#pragma unroll
        for (int c = 0; c < 4; ++c) {
            float v = 0.0f;
            if (ks[c] > pref) {
                v = 1.0f;
            } else if (ks[c] == pref) {
                int s = g4 * 4 + c;
                unsigned int low = (unsigned int)d2key(W[(size_t)b * S + s]);
                v = (low > TL || (low == TL && (unsigned int)s >= sCut)) ? 1.0f : 0.0f;
            }
            ov[c] = v;
        }
        out4[g4] = make_float4(ov[0], ov[1], ov[2], ov[3]);
    }
}

// ---------------------------------------------------------------------------
extern "C" void kernel_launch(void* const* d_in, const int* in_sizes, int n_in,
                              void* d_out, int out_size, void* d_ws, size_t ws_size,
                              hipStream_t stream) {
    const float* x = (const float*)d_in[0];
    float* out = (float*)d_out;

    char* ws = (char*)d_ws;
    size_t off = 0;
    auto alloc = [&](size_t bytes) -> void* {
        void* p = ws + off;
        off += (bytes + 255) & ~(size_t)255;
        return p;
    };

    double* E     = (double*)alloc((size_t)BB * S * sizeof(double));       // 16 MB
    double* Ch    = (double*)alloc((size_t)BB * S * sizeof(double));       // 16 MB
    double* Cc    = (double*)alloc((size_t)BB * S * sizeof(double));       // 16 MB
    double* L     = (double*)alloc((size_t)BB * S * sizeof(double));       // 16 MB
    unsigned int* key32 = (unsigned int*)alloc((size_t)BB * S * sizeof(unsigned int)); // 8 MB
    double* W     = E;  // E dead after gemm_nt -> reuse for weighted
    unsigned int* sc    = (unsigned int*)alloc(64);
    unsigned int* bar   = (unsigned int*)alloc(128);   // 2 cache lines
    int* hist           = (int*)alloc(4 * 2 * 256 * sizeof(int));
    unsigned int* eqcnt = (unsigned int*)alloc(BB * 64);
    unsigned long long* eqpairs =
        (unsigned long long*)alloc((size_t)BB * EQCAP * sizeof(unsigned long long)); // 8 MB

    // 1) pairwise adjacencies (fused per-row stats)
    k_pairwise<<<dim3(N / 64, N / 64, BB), 256, 0, stream>>>(x, E, Ch, Cc);

    // 2) logits = (E @ Ch^T) * 1/8
    k_gemm_nt<<<dim3(N / 64, N / 64, BB), 256, 0, stream>>>(E, Ch, L, 0.125);

    // 3) softmax rows
    k_softmax<<<512, 256, 0, stream>>>(L);

    // 4) weighted = attn @ Cc + key32 epilogue (+ zeroes select scratch)
    k_gemm_nn<<<dim3(N / 64, N / 64, BB), 256, 0, stream>>>(L, Cc, W, key32, bar, hist, eqcnt);

    // 5) fused selection (6 low-contention grid barriers)
    k_select<<<NSELBLK, 256, 0, stream>>>(key32, W, hist, eqcnt, eqpairs, sc, bar, out);
}

// Round 9
// 389.664 us; speedup vs baseline: 1.0470x; 1.0470x over previous
//
#include <hip/hip_runtime.h>
#include <hip/hip_bf16.h>

// Problem constants (from setup_inputs: x = [2, 1024, 64] fp32)
constexpr int BB = 2;
constexpr int N  = 1024;
constexpr int C  = 64;
constexpr int S  = N * N;          // 1048576 = 2^20
constexpr int KSEL = S / 6;        // 174762 entries set to 1 per batch
constexpr int EQCAP   = 1 << 19;   // candidate capacity per batch (~8x margin)
constexpr int NSELBLK = 256;       // select grid == #CUs -> co-resident

typedef double d4 __attribute__((ext_vector_type(4)));

// Order-preserving uint64 mapping of fp64 (monotone: a<b <=> key(a)<key(b))
__device__ __forceinline__ unsigned long long d2key(double d) {
    unsigned long long u = (unsigned long long)__double_as_longlong(d);
    return (u & 0x8000000000000000ULL) ? ~u : (u | 0x8000000000000000ULL);
}

__device__ __forceinline__ unsigned int aload(const unsigned int* p) {
    return __hip_atomic_load(p, __ATOMIC_RELAXED, __HIP_MEMORY_SCOPE_AGENT);
}
__device__ __forceinline__ void astore(unsigned int* p, unsigned int v) {
    (void)__hip_atomic_exchange(p, v, __ATOMIC_RELAXED, __HIP_MEMORY_SCOPE_AGENT);
}

// ---------------------------------------------------------------------------
// K1: pairwise adjacencies with fused per-row stats. 64x64 tile (512 wgs).
__global__ __launch_bounds__(256) void k_pairwise(const float* __restrict__ x,
                                                  double* __restrict__ E,
                                                  double* __restrict__ Ch,
                                                  double* __restrict__ Cc) {
    int b  = blockIdx.z;
    int i0 = blockIdx.y * 64;
    int j0 = blockIdx.x * 64;
    __shared__ double xi[64][65];
    __shared__ double xj[64][65];
    __shared__ double mi[64], ri_[64], si[64];
    __shared__ double mj[64], rj_[64], sj[64];

    int t  = threadIdx.x;
    int r  = t >> 2;
    int cb = (t & 3) * 16;
    const float* xb = x + (size_t)b * N * C;
    {
        const float4* pi = (const float4*)(xb + (size_t)(i0 + r) * C + cb);
        const float4* pj = (const float4*)(xb + (size_t)(j0 + r) * C + cb);
#pragma unroll
        for (int m4 = 0; m4 < 4; ++m4) {
            float4 fi = pi[m4], fj = pj[m4];
            xi[r][cb + 4 * m4 + 0] = (double)fi.x; xi[r][cb + 4 * m4 + 1] = (double)fi.y;
            xi[r][cb + 4 * m4 + 2] = (double)fi.z; xi[r][cb + 4 * m4 + 3] = (double)fi.w;
            xj[r][cb + 4 * m4 + 0] = (double)fj.x; xj[r][cb + 4 * m4 + 1] = (double)fj.y;
            xj[r][cb + 4 * m4 + 2] = (double)fj.z; xj[r][cb + 4 * m4 + 3] = (double)fj.w;
        }
    }
    __syncthreads();

    if (t < 128) {
        int row = t & 63;
        const double (*xs)[65] = (t < 64) ? xi : xj;
        double sum = 0.0, rr = 0.0;
#pragma unroll 8
        for (int c = 0; c < 64; ++c) { double v = xs[row][c]; sum += v; rr = fma(v, v, rr); }
        double m = sum / 64.0;
        double q = 0.0;
#pragma unroll 8
        for (int c = 0; c < 64; ++c) { double w = xs[row][c] - m; q = fma(w, w, q); }
        double sv = 1.0 / sqrt(q);
        if (t < 64) { mi[row] = m; ri_[row] = rr; si[row] = sv; }
        else        { mj[row] = m; rj_[row] = rr; sj[row] = sv; }
    }
    __syncthreads();

    int ty = t >> 4, tx = t & 15;
    double adot[4][4] = {};
    double amax[4][4] = {};
#pragma unroll 8
    for (int c = 0; c < 64; ++c) {
        double ai[4], aj[4];
#pragma unroll
        for (int p = 0; p < 4; ++p) ai[p] = xi[ty + 16 * p][c];
#pragma unroll
        for (int q = 0; q < 4; ++q) aj[q] = xj[tx + 16 * q][c];
#pragma unroll
        for (int p = 0; p < 4; ++p)
#pragma unroll
            for (int q = 0; q < 4; ++q) {
                double d = ai[p] - aj[q];
                amax[p][q] = fmax(amax[p][q], fabs(d));
                adot[p][q] = fma(ai[p], aj[q], adot[p][q]);
            }
    }

#pragma unroll
    for (int p = 0; p < 4; ++p) {
        int li = ty + 16 * p;
        int ii = i0 + li;
        double rri = ri_[li], mmi = mi[li], ssi = si[li];
#pragma unroll
        for (int q = 0; q < 4; ++q) {
            int lj = tx + 16 * q;
            int jj = j0 + lj;
            double dot = adot[p][q];
            double d2  = rri + rj_[lj] - 2.0 * dot;
            double e   = (ii == jj) ? 0.0 : sqrt(fmax(d2, 0.0));
            double cc  = (dot - 64.0 * mmi * mj[lj]) * ssi * sj[lj];
            cc = fmin(1.0, fmax(-1.0, cc));
            size_t idx = (size_t)b * S + (size_t)ii * N + jj;
            E[idx]  = e;
            Ch[idx] = amax[p][q];
            Cc[idx] = cc;
        }
    }
}

// ---------------------------------------------------------------------------
// K2: C = scale * A * B^T (fp64, MFMA). 64x64 tile, 4 waves x 32x32 quadrant,
// LDS double-buffered, BK=32.
__global__ __launch_bounds__(256) void k_gemm_nt(const double* __restrict__ A,
                                                 const double* __restrict__ Bm,
                                                 double* __restrict__ Cm,
                                                 double scale) {
    int b = blockIdx.z;
    const double* Ab = A  + (size_t)b * S;
    const double* Bb = Bm + (size_t)b * S;
    double*       Cb = Cm + (size_t)b * S;
    int i0 = blockIdx.y * 64, j0 = blockIdx.x * 64;

    __shared__ double At[2][64][33];
    __shared__ double Bt[2][64][33];

    int t    = threadIdx.x;
    int lane = t & 63;
    int w    = t >> 6;
    int wr   = (w >> 1) * 32;
    int wc   = (w & 1) * 32;
    int fm   = lane & 15;
    int fk   = lane >> 4;

    int sr = t >> 2, sc0 = (t & 3) * 8;

    d4 acc00 = {0.0, 0.0, 0.0, 0.0};
    d4 acc01 = acc00, acc10 = acc00, acc11 = acc00;

    const double* ap = Ab + (size_t)(i0 + sr) * N + sc0;
    const double* bp = Bb + (size_t)(j0 + sr) * N + sc0;

    double pa[8], pb[8];
#pragma unroll
    for (int m = 0; m < 8; ++m) { pa[m] = ap[m]; pb[m] = bp[m]; }
#pragma unroll
    for (int m = 0; m < 8; ++m) { At[0][sr][sc0 + m] = pa[m]; Bt[0][sr][sc0 + m] = pb[m]; }
    __syncthreads();

    int cur = 0;
    for (int k0 = 0; k0 < N; k0 += 32) {
        bool has_next = (k0 + 32 < N);
        if (has_next) {
            ap += 32; bp += 32;
#pragma unroll
            for (int m = 0; m < 8; ++m) { pa[m] = ap[m]; pb[m] = bp[m]; }
        }
#pragma unroll
        for (int kq = 0; kq < 8; ++kq) {
            int kk = kq * 4 + fk;
            double a0 = At[cur][wr + fm][kk];
            double a1 = At[cur][wr + 16 + fm][kk];
            double b0 = Bt[cur][wc + fm][kk];
            double b1 = Bt[cur][wc + 16 + fm][kk];
            acc00 = __builtin_amdgcn_mfma_f64_16x16x4f64(a0, b0, acc00, 0, 0, 0);
            acc01 = __builtin_amdgcn_mfma_f64_16x16x4f64(a0, b1, acc01, 0, 0, 0);
            acc10 = __builtin_amdgcn_mfma_f64_16x16x4f64(a1, b0, acc10, 0, 0, 0);
            acc11 = __builtin_amdgcn_mfma_f64_16x16x4f64(a1, b1, acc11, 0, 0, 0);
        }
        if (has_next) {
            int nxt = cur ^ 1;
#pragma unroll
            for (int m = 0; m < 8; ++m) { At[nxt][sr][sc0 + m] = pa[m]; Bt[nxt][sr][sc0 + m] = pb[m]; }
            __syncthreads();
            cur = nxt;
        }
    }
    int r0 = i0 + wr + 4 * fk;
    int c0 = j0 + wc + fm;
#pragma unroll
    for (int r = 0; r < 4; ++r) {
        Cb[(size_t)(r0 + r)      * N + c0]      = acc00[r] * scale;
        Cb[(size_t)(r0 + r)      * N + c0 + 16] = acc01[r] * scale;
        Cb[(size_t)(r0 + 16 + r) * N + c0]      = acc10[r] * scale;
        Cb[(size_t)(r0 + 16 + r) * N + c0 + 16] = acc11[r] * scale;
    }
}

// ---------------------------------------------------------------------------
// K4: W = A * B (fp64, MFMA) + key32 epilogue. Block (0,0,0) zeroes all of
// k_select's scratch (barrier tree, hist, candidate counters).
__global__ __launch_bounds__(256) void k_gemm_nn(const double* __restrict__ A,
                                                 const double* __restrict__ Bm,
                                                 double* __restrict__ Wm,
                                                 unsigned int* __restrict__ kq_out,
                                                 unsigned int* __restrict__ bar,
                                                 int* __restrict__ hist,
                                                 unsigned int* __restrict__ eqcnt) {
    if (blockIdx.x == 0 && blockIdx.y == 0 && blockIdx.z == 0) {
        int tt = threadIdx.x;
        for (int i = tt; i < 512; i += 256) bar[i] = 0u;   // tree + release lines
        for (int i = tt; i < 2048; i += 256) hist[i] = 0;
        if (tt < BB) eqcnt[tt * 16] = 0u;                  // one line per batch
    }

    int b = blockIdx.z;
    const double* Ab = A  + (size_t)b * S;
    const double* Bb = Bm + (size_t)b * S;
    double*       Wb = Wm + (size_t)b * S;
    unsigned int* kb = kq_out + (size_t)b * S;
    int i0 = blockIdx.y * 64, j0 = blockIdx.x * 64;

    __shared__ double At[2][64][33];
    __shared__ double Bt[2][32][65];

    int t    = threadIdx.x;
    int lane = t & 63;
    int w    = t >> 6;
    int wr   = (w >> 1) * 32;
    int wc   = (w & 1) * 32;
    int fm   = lane & 15;
    int fk   = lane >> 4;

    int sr = t >> 2, sc0 = (t & 3) * 8;   // A staging: 64 rows x 32 k
    int br = t >> 3, bc = (t & 7) * 8;    // B staging: 32 k x 64 cols

    d4 acc00 = {0.0, 0.0, 0.0, 0.0};
    d4 acc01 = acc00, acc10 = acc00, acc11 = acc00;

    const double* ap = Ab + (size_t)(i0 + sr) * N + sc0;
    const double* bp = Bb + (size_t)br * N + j0 + bc;

    double pa[8], pb[8];
#pragma unroll
    for (int m = 0; m < 8; ++m) { pa[m] = ap[m]; pb[m] = bp[m]; }
#pragma unroll
    for (int m = 0; m < 8; ++m) { At[0][sr][sc0 + m] = pa[m]; Bt[0][br][bc + m] = pb[m]; }
    __syncthreads();

    int cur = 0;
    for (int k0 = 0; k0 < N; k0 += 32) {
        bool has_next = (k0 + 32 < N);
        if (has_next) {
            ap += 32; bp += (size_t)32 * N;
#pragma unroll
            for (int m = 0; m < 8; ++m) { pa[m] = ap[m]; pb[m] = bp[m]; }
        }
#pragma unroll
        for (int kq = 0; kq < 8; ++kq) {
            int kk = kq * 4 + fk;
            double a0 = At[cur][wr + fm][kk];
            double a1 = At[cur][wr + 16 + fm][kk];
            double b0 = Bt[cur][kk][wc + fm];
            double b1 = Bt[cur][kk][wc + 16 + fm];
            acc00 = __builtin_amdgcn_mfma_f64_16x16x4f64(a0, b0, acc00, 0, 0, 0);
            acc01 = __builtin_amdgcn_mfma_f64_16x16x4f64(a0, b1, acc01, 0, 0, 0);
            acc10 = __builtin_amdgcn_mfma_f64_16x16x4f64(a1, b0, acc10, 0, 0, 0);
            acc11 = __builtin_amdgcn_mfma_f64_16x16x4f64(a1, b1, acc11, 0, 0, 0);
        }
        if (has_next) {
            int nxt = cur ^ 1;
#pragma unroll
            for (int m = 0; m < 8; ++m) { At[nxt][sr][sc0 + m] = pa[m]; Bt[nxt][br][bc + m] = pb[m]; }
            __syncthreads();
            cur = nxt;
        }
    }
    int r0 = i0 + wr + 4 * fk;
    int c0 = j0 + wc + fm;
#pragma unroll
    for (int r = 0; r < 4; ++r) {
        double w00 = acc00[r], w01 = acc01[r], w10 = acc10[r], w11 = acc11[r];
        size_t i00 = (size_t)(r0 + r)      * N + c0;
        size_t i01 = (size_t)(r0 + r)      * N + c0 + 16;
        size_t i10 = (size_t)(r0 + 16 + r) * N + c0;
        size_t i11 = (size_t)(r0 + 16 + r) * N + c0 + 16;
        Wb[i00] = w00; kb[i00] = (unsigned int)(d2key(w00) >> 32);
        Wb[i01] = w01; kb[i01] = (unsigned int)(d2key(w01) >> 32);
        Wb[i10] = w10; kb[i10] = (unsigned int)(d2key(w10) >> 32);
        Wb[i11] = w11; kb[i11] = (unsigned int)(d2key(w11) >> 32);
    }
}

// ---------------------------------------------------------------------------
// K3: fp64 row softmax. Wave per row, shuffle-only; 512 wgs.
__global__ __launch_bounds__(256) void k_softmax(double* __restrict__ L) {
    int row = (blockIdx.x << 2) + (threadIdx.x >> 6);
    int ln  = threadIdx.x & 63;
    double* p = L + (size_t)row * N;

    double v[16];
#pragma unroll
    for (int q = 0; q < 16; ++q) v[q] = p[ln + 64 * q];

    double mx = v[0];
#pragma unroll
    for (int q = 1; q < 16; ++q) mx = fmax(mx, v[q]);
#pragma unroll
    for (int off = 32; off >= 1; off >>= 1) mx = fmax(mx, __shfl_xor(mx, off));

    double s = 0.0;
#pragma unroll
    for (int q = 0; q < 16; ++q) { v[q] = exp(v[q] - mx); s += v[q]; }
#pragma unroll
    for (int off = 32; off >= 1; off >>= 1) s += __shfl_xor(s, off);

#pragma unroll
    for (int q = 0; q < 16; ++q) p[ln + 64 * q] = v[q] / s;
}

// ---------------------------------------------------------------------------
// K5: fused selection. 256 co-resident blocks, 5 grid barriers.
// Barrier = TWO-LEVEL arrival tree (16 group counters on private cache lines
// -> 1 root counter -> release flag): same-line RMW serialization drops from
// 256/line to 16/line. Spinners poll the release line with agent-scope loads
// at ~1k-cycle intervals.
__device__ __forceinline__ void gridbar(unsigned int* bar, unsigned int* phase) {
    __syncthreads();
    if (threadIdx.x == 0) {
        asm volatile("s_waitcnt vmcnt(0)" ::: "memory");
        unsigned int ph = ++(*phase);
        int g = (int)(blockIdx.x >> 4);   // 16 groups x 16 blocks
        unsigned int a1 = __hip_atomic_fetch_add(&bar[32 + g * 16], 1u,
                              __ATOMIC_RELAXED, __HIP_MEMORY_SCOPE_AGENT) + 1u;
        if (a1 == ph * 16u) {             // group leader
            unsigned int a2 = __hip_atomic_fetch_add(&bar[0], 1u,
                                  __ATOMIC_RELAXED, __HIP_MEMORY_SCOPE_AGENT) + 1u;
            if (a2 == ph * 16u) astore(&bar[16], ph);   // release (own line)
        }
        while (aload(&bar[16]) < ph) __builtin_amdgcn_s_sleep(16);
        asm volatile("" ::: "memory");
    }
    __syncthreads();
}

__global__ __launch_bounds__(256) void k_select(const unsigned int* __restrict__ key32,
                                                const double* __restrict__ W,
                                                int* __restrict__ hist,      // 4*2*256 ints
                                                unsigned int* __restrict__ eqcnt,
                                                unsigned int* __restrict__ candk,
                                                unsigned long long* __restrict__ cand64,
                                                unsigned int* __restrict__ sc,
                                                unsigned int* __restrict__ bar,
                                                float* __restrict__ out) {
    int blk = blockIdx.x, t = threadIdx.x;
    int b  = blk >> 7;            // 128 blocks per batch
    int lb = blk & 127;
    int lane = t & 63;
    unsigned int phase = 0;

    __shared__ int lh[256];
    __shared__ unsigned int s_pref, s_kneed;

    const uint4* k4 = (const uint4*)(key32 + (size_t)b * S);
    unsigned int pref = 0, kneed = (unsigned int)KSEL;

    unsigned int* ecnt = &eqcnt[b * 16];
    unsigned int* ck = candk + (size_t)b * EQCAP;
    unsigned long long* c64 = cand64 + (size_t)b * EQCAP;
    unsigned long long lmask = (lane == 63) ? ~0ULL : ((1ULL << (lane + 1)) - 1ULL);
    lmask >>= 1;   // bits strictly below this lane

    // ---- 4 radix passes; pass 3 also collects 24-bit-prefix candidates ----
    for (int p = 0; p < 4; ++p) {
        int shift = 24 - 8 * p;
        lh[t] = 0;
        __syncthreads();
        unsigned int prefh = (p == 0) ? 0u : (pref >> (shift + 8));
        for (int it = 0; it < 8; ++it) {
            int g4 = (it * 128 + lb) * 256 + t;
            uint4 kv = k4[g4];
            unsigned int ks[4] = {kv.x, kv.y, kv.z, kv.w};
#pragma unroll
            for (int c = 0; c < 4; ++c) {
                bool match = (p == 0) || ((ks[c] >> (shift + 8)) == prefh);
                if (match) atomicAdd(&lh[(ks[c] >> shift) & 255u], 1);
                if (p == 3) {
                    unsigned long long mb = __ballot(match);
                    if (mb != 0ULL) {
                        int ldr = __ffsll((long long)mb) - 1;
                        unsigned int base = 0;
                        if (lane == ldr)
                            base = __hip_atomic_fetch_add(ecnt, (unsigned int)__popcll(mb),
                                                          __ATOMIC_RELAXED,
                                                          __HIP_MEMORY_SCOPE_AGENT);
                        base = __shfl(base, ldr, 64);
                        if (match) {
                            unsigned int pos = base + (unsigned int)__popcll(mb & lmask);
                            if (pos < (unsigned int)EQCAP) {
                                int s = g4 * 4 + c;
                                unsigned int low = (unsigned int)d2key(W[(size_t)b * S + s]);
                                astore(&ck[pos], ks[c]);
                                unsigned long long pr =
                                    ((unsigned long long)(unsigned int)s << 32) | low;
                                (void)__hip_atomic_exchange(&c64[pos], pr, __ATOMIC_RELAXED,
                                                            __HIP_MEMORY_SCOPE_AGENT);
                            }
                        }
                    }
                }
            }
        }
        __syncthreads();
        if (lh[t] != 0)
            __hip_atomic_fetch_add((unsigned int*)&hist[(p * 2 + b) * 256 + t],
                                   (unsigned int)lh[t], __ATOMIC_RELAXED,
                                   __HIP_MEMORY_SCOPE_AGENT);
        gridbar(bar, &phase);
        lh[t] = (int)aload((const unsigned int*)&hist[(p * 2 + b) * 256 + t]);
        __syncthreads();
        if (t == 0) {
            unsigned int cum = 0; int bucket = 0;
            for (int i = 255; i >= 0; --i) {
                unsigned int h = (unsigned int)lh[i];
                if (cum + h >= kneed) { bucket = i; break; }
                cum += h;
            }
            s_pref  = pref | ((unsigned int)bucket << shift);
            s_kneed = kneed - cum;
        }
        __syncthreads();
        pref = s_pref; kneed = s_kneed;
        __syncthreads();
    }

    // ---- refine (one block per batch): filter key32==T32 among candidates,
    //      4 passes low32 + 3 passes idx ----
    if (lb == 0) {
        unsigned int cnt = aload(ecnt);
        if (cnt > (unsigned int)EQCAP) cnt = EQCAP;
        unsigned int rpref = 0, rkneed = kneed;
        for (int shift = 24; shift >= 0; shift -= 8) {
            lh[t] = 0;
            __syncthreads();
            unsigned int ph = (shift == 24) ? 0u : (rpref >> (shift + 8));
            for (unsigned int e = t; e < cnt; e += 256) {
                if (ck[e] != pref) continue;                 // plain loads: lines only
                unsigned int low = (unsigned int)c64[e];     // ever atomically written
                bool match = (shift == 24) || ((low >> (shift + 8)) == ph);
                if (match) atomicAdd(&lh[(low >> shift) & 255u], 1);
            }
            __syncthreads();
            if (t == 0) {
                unsigned int cum = 0; int bucket = 0;
                for (int i = 255; i >= 0; --i) {
                    unsigned int h = (unsigned int)lh[i];
                    if (cum + h >= rkneed) { bucket = i; break; }
                    cum += h;
                }
                s_pref  = rpref | ((unsigned int)bucket << shift);
                s_kneed = rkneed - cum;
            }
            __syncthreads();
            rpref = s_pref; rkneed = s_kneed;
            __syncthreads();
        }
        unsigned int TL = rpref;
        unsigned int ipref = 0;
        for (int shift = 16; shift >= 0; shift -= 8) {
            lh[t] = 0;
            __syncthreads();
            unsigned int ph = (shift == 16) ? 0u : (ipref >> (shift + 8));
            for (unsigned int e = t; e < cnt; e += 256) {
                if (ck[e] != pref) continue;
                unsigned long long pr = c64[e];
                unsigned int low = (unsigned int)pr;
                if (low != TL) continue;
                unsigned int idx = (unsigned int)(pr >> 32);
                bool match = (shift == 16) || ((idx >> (shift + 8)) == ph);
                if (match) atomicAdd(&lh[(idx >> shift) & 255u], 1);
            }
            __syncthreads();
            if (t == 0) {
                unsigned int cum = 0; int bucket = 0;
                for (int i = 255; i >= 0; --i) {
                    unsigned int h = (unsigned int)lh[i];
                    if (cum + h >= rkneed) { bucket = i; break; }
                    cum += h;
                }
                s_pref  = ipref | ((unsigned int)bucket << shift);
                s_kneed = rkneed - cum;
            }
            __syncthreads();
            ipref = s_pref; rkneed = s_kneed;
            __syncthreads();
        }
        if (t == 0) { astore(&sc[2 * b], TL); astore(&sc[2 * b + 1], ipref); }
    }
    gridbar(bar, &phase);

    // ---- final mask ----
    unsigned int TL   = aload(&sc[2 * b]);
    unsigned int sCut = aload(&sc[2 * b + 1]);
    float4* out4 = (float4*)(out + (size_t)b * S);
    for (int it = 0; it < 8; ++it) {
        int g4 = (it * 128 + lb) * 256 + t;
        uint4 kv = k4[g4];
        unsigned int ks[4] = {kv.x, kv.y, kv.z, kv.w};
        float ov[4];
#pragma unroll
        for (int c = 0; c < 4; ++c) {
            float v = 0.0f;
            if (ks[c] > pref) {
                v = 1.0f;
            } else if (ks[c] == pref) {
                int s = g4 * 4 + c;
                unsigned int low = (unsigned int)d2key(W[(size_t)b * S + s]);
                v = (low > TL || (low == TL && (unsigned int)s >= sCut)) ? 1.0f : 0.0f;
            }
            ov[c] = v;
        }
        out4[g4] = make_float4(ov[0], ov[1], ov[2], ov[3]);
    }
}

// ---------------------------------------------------------------------------
extern "C" void kernel_launch(void* const* d_in, const int* in_sizes, int n_in,
                              void* d_out, int out_size, void* d_ws, size_t ws_size,
                              hipStream_t stream) {
    const float* x = (const float*)d_in[0];
    float* out = (float*)d_out;

    char* ws = (char*)d_ws;
    size_t off = 0;
    auto alloc = [&](size_t bytes) -> void* {
        void* p = ws + off;
        off += (bytes + 255) & ~(size_t)255;
        return p;
    };

    double* E     = (double*)alloc((size_t)BB * S * sizeof(double));       // 16 MB
    double* Ch    = (double*)alloc((size_t)BB * S * sizeof(double));       // 16 MB
    double* Cc    = (double*)alloc((size_t)BB * S * sizeof(double));       // 16 MB
    double* L     = (double*)alloc((size_t)BB * S * sizeof(double));       // 16 MB
    unsigned int* key32 = (unsigned int*)alloc((size_t)BB * S * sizeof(unsigned int)); // 8 MB
    double* W     = E;  // E dead after gemm_nt -> reuse for weighted
    unsigned int* sc    = (unsigned int*)alloc(64);
    unsigned int* bar   = (unsigned int*)alloc(2048);  // barrier tree (32 lines)
    int* hist           = (int*)alloc(4 * 2 * 256 * sizeof(int));
    unsigned int* eqcnt = (unsigned int*)alloc(BB * 64);
    unsigned int* candk = (unsigned int*)alloc((size_t)BB * EQCAP * sizeof(unsigned int));       // 4 MB
    unsigned long long* cand64 =
        (unsigned long long*)alloc((size_t)BB * EQCAP * sizeof(unsigned long long));             // 8 MB

    // 1) pairwise adjacencies (fused per-row stats)
    k_pairwise<<<dim3(N / 64, N / 64, BB), 256, 0, stream>>>(x, E, Ch, Cc);

    // 2) logits = (E @ Ch^T) * 1/8
    k_gemm_nt<<<dim3(N / 64, N / 64, BB), 256, 0, stream>>>(E, Ch, L, 0.125);

    // 3) softmax rows
    k_softmax<<<512, 256, 0, stream>>>(L);

    // 4) weighted = attn @ Cc + key32 epilogue (+ zeroes select scratch)
    k_gemm_nn<<<dim3(N / 64, N / 64, BB), 256, 0, stream>>>(L, Cc, W, key32, bar, hist, eqcnt);

    // 5) fused selection (5 tree-arrival grid barriers)
    k_select<<<NSELBLK, 256, 0, stream>>>(key32, W, hist, eqcnt, candk, cand64, sc, bar, out);
}

// Round 10
// 384.045 us; speedup vs baseline: 1.0624x; 1.0146x over previous
//
#include <hip/hip_runtime.h>
#include <hip/hip_bf16.h>

// Problem constants (from setup_inputs: x = [2, 1024, 64] fp32)
constexpr int BB = 2;
constexpr int N  = 1024;
constexpr int C  = 64;
constexpr int S  = N * N;          // 1048576 = 2^20
constexpr int KSEL = S / 6;        // 174762 entries set to 1 per batch
constexpr int EQCAP   = 1 << 17;   // exact-tie capacity per batch (~32x margin)
constexpr int NSELBLK = 256;       // select grid == #CUs -> co-resident

typedef double d4 __attribute__((ext_vector_type(4)));

// Order-preserving uint64 mapping of fp64 (monotone: a<b <=> key(a)<key(b))
__device__ __forceinline__ unsigned long long d2key(double d) {
    unsigned long long u = (unsigned long long)__double_as_longlong(d);
    return (u & 0x8000000000000000ULL) ? ~u : (u | 0x8000000000000000ULL);
}

__device__ __forceinline__ unsigned int aload(const unsigned int* p) {
    return __hip_atomic_load(p, __ATOMIC_RELAXED, __HIP_MEMORY_SCOPE_AGENT);
}
__device__ __forceinline__ void astore(unsigned int* p, unsigned int v) {
    (void)__hip_atomic_exchange(p, v, __ATOMIC_RELAXED, __HIP_MEMORY_SCOPE_AGENT);
}
__device__ __forceinline__ unsigned long long aload64(const unsigned long long* p) {
    return __hip_atomic_load(p, __ATOMIC_RELAXED, __HIP_MEMORY_SCOPE_AGENT);
}
__device__ __forceinline__ void astore64(unsigned long long* p, unsigned long long v) {
    (void)__hip_atomic_exchange(p, v, __ATOMIC_RELAXED, __HIP_MEMORY_SCOPE_AGENT);
}

// ---------------------------------------------------------------------------
// K1: pairwise adjacencies with fused per-row stats. 64x64 tile (512 wgs).
__global__ __launch_bounds__(256) void k_pairwise(const float* __restrict__ x,
                                                  double* __restrict__ E,
                                                  double* __restrict__ Ch,
                                                  double* __restrict__ Cc) {
    int b  = blockIdx.z;
    int i0 = blockIdx.y * 64;
    int j0 = blockIdx.x * 64;
    __shared__ double xi[64][65];
    __shared__ double xj[64][65];
    __shared__ double mi[64], ri_[64], si[64];
    __shared__ double mj[64], rj_[64], sj[64];

    int t  = threadIdx.x;
    int r  = t >> 2;
    int cb = (t & 3) * 16;
    const float* xb = x + (size_t)b * N * C;
    {
        const float4* pi = (const float4*)(xb + (size_t)(i0 + r) * C + cb);
        const float4* pj = (const float4*)(xb + (size_t)(j0 + r) * C + cb);
#pragma unroll
        for (int m4 = 0; m4 < 4; ++m4) {
            float4 fi = pi[m4], fj = pj[m4];
            xi[r][cb + 4 * m4 + 0] = (double)fi.x; xi[r][cb + 4 * m4 + 1] = (double)fi.y;
            xi[r][cb + 4 * m4 + 2] = (double)fi.z; xi[r][cb + 4 * m4 + 3] = (double)fi.w;
            xj[r][cb + 4 * m4 + 0] = (double)fj.x; xj[r][cb + 4 * m4 + 1] = (double)fj.y;
            xj[r][cb + 4 * m4 + 2] = (double)fj.z; xj[r][cb + 4 * m4 + 3] = (double)fj.w;
        }
    }
    __syncthreads();

    if (t < 128) {
        int row = t & 63;
        const double (*xs)[65] = (t < 64) ? xi : xj;
        double sum = 0.0, rr = 0.0;
#pragma unroll 8
        for (int c = 0; c < 64; ++c) { double v = xs[row][c]; sum += v; rr = fma(v, v, rr); }
        double m = sum / 64.0;
        double q = 0.0;
#pragma unroll 8
        for (int c = 0; c < 64; ++c) { double w = xs[row][c] - m; q = fma(w, w, q); }
        double sv = 1.0 / sqrt(q);
        if (t < 64) { mi[row] = m; ri_[row] = rr; si[row] = sv; }
        else        { mj[row] = m; rj_[row] = rr; sj[row] = sv; }
    }
    __syncthreads();

    int ty = t >> 4, tx = t & 15;
    double adot[4][4] = {};
    double amax[4][4] = {};
#pragma unroll 8
    for (int c = 0; c < 64; ++c) {
        double ai[4], aj[4];
#pragma unroll
        for (int p = 0; p < 4; ++p) ai[p] = xi[ty + 16 * p][c];
#pragma unroll
        for (int q = 0; q < 4; ++q) aj[q] = xj[tx + 16 * q][c];
#pragma unroll
        for (int p = 0; p < 4; ++p)
#pragma unroll
            for (int q = 0; q < 4; ++q) {
                double d = ai[p] - aj[q];
                amax[p][q] = fmax(amax[p][q], fabs(d));
                adot[p][q] = fma(ai[p], aj[q], adot[p][q]);
            }
    }

#pragma unroll
    for (int p = 0; p < 4; ++p) {
        int li = ty + 16 * p;
        int ii = i0 + li;
        double rri = ri_[li], mmi = mi[li], ssi = si[li];
#pragma unroll
        for (int q = 0; q < 4; ++q) {
            int lj = tx + 16 * q;
            int jj = j0 + lj;
            double dot = adot[p][q];
            double d2  = rri + rj_[lj] - 2.0 * dot;
            double e   = (ii == jj) ? 0.0 : sqrt(fmax(d2, 0.0));
            double cc  = (dot - 64.0 * mmi * mj[lj]) * ssi * sj[lj];
            cc = fmin(1.0, fmax(-1.0, cc));
            size_t idx = (size_t)b * S + (size_t)ii * N + jj;
            E[idx]  = e;
            Ch[idx] = amax[p][q];
            Cc[idx] = cc;
        }
    }
}

// ---------------------------------------------------------------------------
// K2: C = scale * A * B^T (fp64, MFMA). 64x64 tile, 4 waves x 32x32 quadrant,
// LDS double-buffered, BK=32.
__global__ __launch_bounds__(256) void k_gemm_nt(const double* __restrict__ A,
                                                 const double* __restrict__ Bm,
                                                 double* __restrict__ Cm,
                                                 double scale) {
    int b = blockIdx.z;
    const double* Ab = A  + (size_t)b * S;
    const double* Bb = Bm + (size_t)b * S;
    double*       Cb = Cm + (size_t)b * S;
    int i0 = blockIdx.y * 64, j0 = blockIdx.x * 64;

    __shared__ double At[2][64][33];
    __shared__ double Bt[2][64][33];

    int t    = threadIdx.x;
    int lane = t & 63;
    int w    = t >> 6;
    int wr   = (w >> 1) * 32;
    int wc   = (w & 1) * 32;
    int fm   = lane & 15;
    int fk   = lane >> 4;

    int sr = t >> 2, sc0 = (t & 3) * 8;

    d4 acc00 = {0.0, 0.0, 0.0, 0.0};
    d4 acc01 = acc00, acc10 = acc00, acc11 = acc00;

    const double* ap = Ab + (size_t)(i0 + sr) * N + sc0;
    const double* bp = Bb + (size_t)(j0 + sr) * N + sc0;

    double pa[8], pb[8];
#pragma unroll
    for (int m = 0; m < 8; ++m) { pa[m] = ap[m]; pb[m] = bp[m]; }
#pragma unroll
    for (int m = 0; m < 8; ++m) { At[0][sr][sc0 + m] = pa[m]; Bt[0][sr][sc0 + m] = pb[m]; }
    __syncthreads();

    int cur = 0;
    for (int k0 = 0; k0 < N; k0 += 32) {
        bool has_next = (k0 + 32 < N);
        if (has_next) {
            ap += 32; bp += 32;
#pragma unroll
            for (int m = 0; m < 8; ++m) { pa[m] = ap[m]; pb[m] = bp[m]; }
        }
#pragma unroll
        for (int kq = 0; kq < 8; ++kq) {
            int kk = kq * 4 + fk;
            double a0 = At[cur][wr + fm][kk];
            double a1 = At[cur][wr + 16 + fm][kk];
            double b0 = Bt[cur][wc + fm][kk];
            double b1 = Bt[cur][wc + 16 + fm][kk];
            acc00 = __builtin_amdgcn_mfma_f64_16x16x4f64(a0, b0, acc00, 0, 0, 0);
            acc01 = __builtin_amdgcn_mfma_f64_16x16x4f64(a0, b1, acc01, 0, 0, 0);
            acc10 = __builtin_amdgcn_mfma_f64_16x16x4f64(a1, b0, acc10, 0, 0, 0);
            acc11 = __builtin_amdgcn_mfma_f64_16x16x4f64(a1, b1, acc11, 0, 0, 0);
        }
        if (has_next) {
            int nxt = cur ^ 1;
#pragma unroll
            for (int m = 0; m < 8; ++m) { At[nxt][sr][sc0 + m] = pa[m]; Bt[nxt][sr][sc0 + m] = pb[m]; }
            __syncthreads();
            cur = nxt;
        }
    }
    int r0 = i0 + wr + 4 * fk;
    int c0 = j0 + wc + fm;
#pragma unroll
    for (int r = 0; r < 4; ++r) {
        Cb[(size_t)(r0 + r)      * N + c0]      = acc00[r] * scale;
        Cb[(size_t)(r0 + r)      * N + c0 + 16] = acc01[r] * scale;
        Cb[(size_t)(r0 + 16 + r) * N + c0]      = acc10[r] * scale;
        Cb[(size_t)(r0 + 16 + r) * N + c0 + 16] = acc11[r] * scale;
    }
}

// ---------------------------------------------------------------------------
// K4: W = A * B (fp64, MFMA) + key32 epilogue. Block (0,0,0) zeroes all of
// k_select's scratch (barrier tree, group hists, counters, publish lines).
__global__ __launch_bounds__(256) void k_gemm_nn(const double* __restrict__ A,
                                                 const double* __restrict__ Bm,
                                                 double* __restrict__ Wm,
                                                 unsigned int* __restrict__ kq_out,
                                                 unsigned int* __restrict__ bar,
                                                 unsigned int* __restrict__ ghist,
                                                 unsigned int* __restrict__ eqcnt,
                                                 unsigned long long* __restrict__ pubA,
                                                 unsigned long long* __restrict__ pubR) {
    if (blockIdx.x == 0 && blockIdx.y == 0 && blockIdx.z == 0) {
        int tt = threadIdx.x;
        for (int i = tt; i < 512; i += 256) bar[i] = 0u;
        for (int i = tt; i < 4 * 2 * 16 * 256; i += 256) ghist[i] = 0u;
        if (tt < 32) eqcnt[tt] = 0u;
        if (tt < 16) { pubA[tt] = 0ULL; pubR[tt] = 0ULL; }
    }

    int b = blockIdx.z;
    const double* Ab = A  + (size_t)b * S;
    const double* Bb = Bm + (size_t)b * S;
    double*       Wb = Wm + (size_t)b * S;
    unsigned int* kb = kq_out + (size_t)b * S;
    int i0 = blockIdx.y * 64, j0 = blockIdx.x * 64;

    __shared__ double At[2][64][33];
    __shared__ double Bt[2][32][65];

    int t    = threadIdx.x;
    int lane = t & 63;
    int w    = t >> 6;
    int wr   = (w >> 1) * 32;
    int wc   = (w & 1) * 32;
    int fm   = lane & 15;
    int fk   = lane >> 4;

    int sr = t >> 2, sc0 = (t & 3) * 8;   // A staging: 64 rows x 32 k
    int br = t >> 3, bc = (t & 7) * 8;    // B staging: 32 k x 64 cols

    d4 acc00 = {0.0, 0.0, 0.0, 0.0};
    d4 acc01 = acc00, acc10 = acc00, acc11 = acc00;

    const double* ap = Ab + (size_t)(i0 + sr) * N + sc0;
    const double* bp = Bb + (size_t)br * N + j0 + bc;

    double pa[8], pb[8];
#pragma unroll
    for (int m = 0; m < 8; ++m) { pa[m] = ap[m]; pb[m] = bp[m]; }
#pragma unroll
    for (int m = 0; m < 8; ++m) { At[0][sr][sc0 + m] = pa[m]; Bt[0][br][bc + m] = pb[m]; }
    __syncthreads();

    int cur = 0;
    for (int k0 = 0; k0 < N; k0 += 32) {
        bool has_next = (k0 + 32 < N);
        if (has_next) {
            ap += 32; bp += (size_t)32 * N;
#pragma unroll
            for (int m = 0; m < 8; ++m) { pa[m] = ap[m]; pb[m] = bp[m]; }
        }
#pragma unroll
        for (int kq = 0; kq < 8; ++kq) {
            int kk = kq * 4 + fk;
            double a0 = At[cur][wr + fm][kk];
            double a1 = At[cur][wr + 16 + fm][kk];
            double b0 = Bt[cur][kk][wc + fm];
            double b1 = Bt[cur][kk][wc + 16 + fm];
            acc00 = __builtin_amdgcn_mfma_f64_16x16x4f64(a0, b0, acc00, 0, 0, 0);
            acc01 = __builtin_amdgcn_mfma_f64_16x16x4f64(a0, b1, acc01, 0, 0, 0);
            acc10 = __builtin_amdgcn_mfma_f64_16x16x4f64(a1, b0, acc10, 0, 0, 0);
            acc11 = __builtin_amdgcn_mfma_f64_16x16x4f64(a1, b1, acc11, 0, 0, 0);
        }
        if (has_next) {
            int nxt = cur ^ 1;
#pragma unroll
            for (int m = 0; m < 8; ++m) { At[nxt][sr][sc0 + m] = pa[m]; Bt[nxt][br][bc + m] = pb[m]; }
            __syncthreads();
            cur = nxt;
        }
    }
    int r0 = i0 + wr + 4 * fk;
    int c0 = j0 + wc + fm;
#pragma unroll
    for (int r = 0; r < 4; ++r) {
        double w00 = acc00[r], w01 = acc01[r], w10 = acc10[r], w11 = acc11[r];
        size_t i00 = (size_t)(r0 + r)      * N + c0;
        size_t i01 = (size_t)(r0 + r)      * N + c0 + 16;
        size_t i10 = (size_t)(r0 + 16 + r) * N + c0;
        size_t i11 = (size_t)(r0 + 16 + r) * N + c0 + 16;
        Wb[i00] = w00; kb[i00] = (unsigned int)(d2key(w00) >> 32);
        Wb[i01] = w01; kb[i01] = (unsigned int)(d2key(w01) >> 32);
        Wb[i10] = w10; kb[i10] = (unsigned int)(d2key(w10) >> 32);
        Wb[i11] = w11; kb[i11] = (unsigned int)(d2key(w11) >> 32);
    }
}

// ---------------------------------------------------------------------------
// K3: fp64 row softmax. Wave per row, shuffle-only; 512 wgs.
__global__ __launch_bounds__(256) void k_softmax(double* __restrict__ L) {
    int row = (blockIdx.x << 2) + (threadIdx.x >> 6);
    int ln  = threadIdx.x & 63;
    double* p = L + (size_t)row * N;

    double v[16];
#pragma unroll
    for (int q = 0; q < 16; ++q) v[q] = p[ln + 64 * q];

    double mx = v[0];
#pragma unroll
    for (int q = 1; q < 16; ++q) mx = fmax(mx, v[q]);
#pragma unroll
    for (int off = 32; off >= 1; off >>= 1) mx = fmax(mx, __shfl_xor(mx, off));

    double s = 0.0;
#pragma unroll
    for (int q = 0; q < 16; ++q) { v[q] = exp(v[q] - mx); s += v[q]; }
#pragma unroll
    for (int off = 32; off >= 1; off >>= 1) s += __shfl_xor(s, off);

#pragma unroll
    for (int q = 0; q < 16; ++q) p[ln + 64 * q] = v[q] / s;
}

// ---------------------------------------------------------------------------
// K5: fused selection, 5 grid barriers. XCD-aligned tile ownership (block i
// reads tiles written by gemm_nn blocks with same dispatch%8 residue), group
// hists (16 groups/batch -> 128 RMW/line), leader-scan + tagged 64-bit
// publish (no grid-wide hist readback).
__device__ __forceinline__ void gridbar(unsigned int* bar, unsigned int* phase) {
    asm volatile("s_waitcnt vmcnt(0)" ::: "memory");   // every wave drains its mem ops
    __syncthreads();
    if (threadIdx.x == 0) {
        unsigned int ph = ++(*phase);
        int g = (int)(blockIdx.x >> 4);   // 16 groups x 16 blocks
        unsigned int a1 = __hip_atomic_fetch_add(&bar[32 + g * 16], 1u,
                              __ATOMIC_RELAXED, __HIP_MEMORY_SCOPE_AGENT) + 1u;
        if (a1 == ph * 16u) {
            unsigned int a2 = __hip_atomic_fetch_add(&bar[0], 1u,
                                  __ATOMIC_RELAXED, __HIP_MEMORY_SCOPE_AGENT) + 1u;
            if (a2 == ph * 16u) astore(&bar[16], ph);
        }
        while (aload(&bar[16]) < ph) __builtin_amdgcn_s_sleep(4);
        asm volatile("" ::: "memory");
    }
    __syncthreads();
}

__global__ __launch_bounds__(256) void k_select(const unsigned int* __restrict__ key32,
                                                const double* __restrict__ W,
                                                unsigned int* __restrict__ ghist,
                                                unsigned int* __restrict__ eqcnt,
                                                unsigned long long* __restrict__ cand,
                                                unsigned long long* __restrict__ pubA,
                                                unsigned long long* __restrict__ pubR,
                                                unsigned int* __restrict__ bar,
                                                float* __restrict__ out) {
    int blk = blockIdx.x, t = threadIdx.x;
    int b  = blk >> 7;            // 128 blocks per batch
    int lb = blk & 127;
    int lane = t & 63, wv = t >> 6;
    bool leader = (lb == 0);
    unsigned int phase = 0;

    __shared__ int lh[256];
    __shared__ int wtot[4];
    __shared__ unsigned int sbase;
    __shared__ unsigned long long s_pub;

    // XCD-aligned tile ownership: residue r8 = blk%8, two tiles per block.
    int r8 = blk & 7;
    int o  = lb >> 3;                       // 0..15
    int tf0 = r8 + 16 * o;                  // flats r8+8*(2o), r8+8*(2o+1)
    int tf1 = tf0 + 8;
    int rr = t >> 2, c16 = (t & 3) * 16;
    int tb[2];
    tb[0] = ((tf0 >> 4) * 64 + rr) * N + (tf0 & 15) * 64 + c16;
    tb[1] = ((tf1 >> 4) * 64 + rr) * N + (tf1 & 15) * 64 + c16;

    const unsigned int* kb = key32 + (size_t)b * S;
    const double*       Wb = W     + (size_t)b * S;
    unsigned long long* myPubA = &pubA[b * 8];
    unsigned long long* myPubR = &pubR[b * 8];

    unsigned int pref = 0, kneed = (unsigned int)KSEL;

    // ---- stage A: 4 radix passes, leader-scan + tagged publish ----
    for (int p = 0; p < 4; ++p) {
        int shift = 24 - 8 * p;
        lh[t] = 0;
        __syncthreads();
#pragma unroll
        for (int u = 0; u < 2; ++u)
#pragma unroll
            for (int m4 = 0; m4 < 4; ++m4) {
                uint4 kv = *(const uint4*)(kb + tb[u] + 4 * m4);
                unsigned int ks[4] = {kv.x, kv.y, kv.z, kv.w};
#pragma unroll
                for (int c = 0; c < 4; ++c) {
                    bool match = (((unsigned long long)(ks[c] ^ pref)) >> (shift + 8)) == 0ULL;
                    if (match) atomicAdd(&lh[(ks[c] >> shift) & 255u], 1);
                }
            }
        __syncthreads();
        if (lh[t] != 0)
            __hip_atomic_fetch_add(&ghist[((p * 2 + b) * 16 + (lb >> 3)) * 256 + t],
                                   (unsigned int)lh[t], __ATOMIC_RELAXED,
                                   __HIP_MEMORY_SCOPE_AGENT);
        gridbar(bar, &phase);

        if (leader) {
            unsigned int sum = 0;
#pragma unroll
            for (int g = 0; g < 16; ++g)
                sum += aload(&ghist[((p * 2 + b) * 16 + g) * 256 + t]);
            lh[t] = (int)sum;
            __syncthreads();
            if (t == 0) {
                unsigned int cum = 0; int bucket = 0;
                for (int i = 255; i >= 0; --i) {
                    unsigned int h = (unsigned int)lh[i];
                    if (cum + h >= kneed) { bucket = i; break; }
                    cum += h;
                }
                unsigned int npref  = pref | ((unsigned int)bucket << shift);
                unsigned int nkneed = kneed - cum;
                astore64(myPubA, (((unsigned long long)(p + 1)) << 56) |
                                 (((unsigned long long)npref) << 24) |
                                 (unsigned long long)nkneed);
                s_pub = (((unsigned long long)(p + 1)) << 56) |
                        (((unsigned long long)npref) << 24) | (unsigned long long)nkneed;
            }
            __syncthreads();
        } else {
            if (t == 0) {
                unsigned long long v;
                while (((v = aload64(myPubA)) >> 56) != (unsigned long long)(p + 1))
                    __builtin_amdgcn_s_sleep(4);
                s_pub = v;
            }
            __syncthreads();
        }
        unsigned long long v = s_pub;
        pref  = (unsigned int)((v >> 24) & 0xFFFFFFFFULL);
        kneed = (unsigned int)(v & 0x3FFFFULL);
        __syncthreads();
    }

    // ---- collect exact ties (key32 == pref): block-aggregated counter ----
    unsigned long long lmask = (1ULL << lane) - 1ULL;   // bits strictly below lane
    unsigned long long* cb = cand + (size_t)b * EQCAP;
    {
        int wcnt = 0;
#pragma unroll
        for (int u = 0; u < 2; ++u)
#pragma unroll
            for (int m4 = 0; m4 < 4; ++m4) {
                uint4 kv = *(const uint4*)(kb + tb[u] + 4 * m4);
                unsigned int ks[4] = {kv.x, kv.y, kv.z, kv.w};
#pragma unroll
                for (int c = 0; c < 4; ++c) {
                    unsigned long long mb = __ballot(ks[c] == pref);
                    wcnt += (int)__popcll(mb);
                }
            }
        if (lane == 0) wtot[wv] = wcnt;
        __syncthreads();
        if (t == 0) {
            int tot = wtot[0] + wtot[1] + wtot[2] + wtot[3];
            sbase = (tot > 0)
                ? __hip_atomic_fetch_add(&eqcnt[b * 16], (unsigned int)tot,
                                         __ATOMIC_RELAXED, __HIP_MEMORY_SCOPE_AGENT)
                : 0u;
        }
        __syncthreads();
        unsigned int wb2 = sbase;
        for (int w2 = 0; w2 < wv; ++w2) wb2 += (unsigned int)wtot[w2];
#pragma unroll
        for (int u = 0; u < 2; ++u)
#pragma unroll
            for (int m4 = 0; m4 < 4; ++m4) {
                uint4 kv = *(const uint4*)(kb + tb[u] + 4 * m4);
                unsigned int ks[4] = {kv.x, kv.y, kv.z, kv.w};
#pragma unroll
                for (int c = 0; c < 4; ++c) {
                    bool m = (ks[c] == pref);
                    unsigned long long mb = __ballot(m);
                    if (m) {
                        unsigned int pos = wb2 + (unsigned int)__popcll(mb & lmask);
                        if (pos < (unsigned int)EQCAP) {
                            int s = tb[u] + 4 * m4 + c;
                            unsigned int low = (unsigned int)d2key(Wb[s]);
                            astore64(&cb[pos],
                                     (((unsigned long long)(unsigned int)s) << 32) | low);
                        }
                    }
                    wb2 += (unsigned int)__popcll(mb);
                }
            }
    }
    gridbar(bar, &phase);   // barrier #5

    // ---- refine (leader block per batch): 4 passes low32 + 3 passes idx ----
    if (leader) {
        unsigned int cnt = aload(&eqcnt[b * 16]);
        if (cnt > (unsigned int)EQCAP) cnt = EQCAP;
        unsigned int rpref = 0, rkneed = kneed;
        for (int shift = 24; shift >= 0; shift -= 8) {
            lh[t] = 0;
            __syncthreads();
            for (unsigned int e = t; e < cnt; e += 256) {
                unsigned int low = (unsigned int)aload64(&cb[e]);
                if ((((unsigned long long)(low ^ rpref)) >> (shift + 8)) == 0ULL)
                    atomicAdd(&lh[(low >> shift) & 255u], 1);
            }
            __syncthreads();
            if (t == 0) {
                unsigned int cum = 0; int bucket = 0;
                for (int i = 255; i >= 0; --i) {
                    unsigned int h = (unsigned int)lh[i];
                    if (cum + h >= rkneed) { bucket = i; break; }
                    cum += h;
                }
                sbase = rpref | ((unsigned int)bucket << shift);
                wtot[0] = (int)(rkneed - cum);
            }
            __syncthreads();
            rpref = sbase; rkneed = (unsigned int)wtot[0];
            __syncthreads();
        }
        unsigned int TL = rpref;
        unsigned int ipref = 0;
        for (int shift = 16; shift >= 0; shift -= 8) {
            lh[t] = 0;
            __syncthreads();
            for (unsigned int e = t; e < cnt; e += 256) {
                unsigned long long pr = aload64(&cb[e]);
                if ((unsigned int)pr != TL) continue;
                unsigned int idx = (unsigned int)(pr >> 32);
                if ((((unsigned long long)(idx ^ ipref)) >> (shift + 8)) == 0ULL)
                    atomicAdd(&lh[(idx >> shift) & 255u], 1);
            }
            __syncthreads();
            if (t == 0) {
                unsigned int cum = 0; int bucket = 0;
                for (int i = 255; i >= 0; --i) {
                    unsigned int h = (unsigned int)lh[i];
                    if (cum + h >= rkneed) { bucket = i; break; }
                    cum += h;
                }
                sbase = ipref | ((unsigned int)bucket << shift);
                wtot[0] = (int)(rkneed - cum);
            }
            __syncthreads();
            ipref = sbase; rkneed = (unsigned int)wtot[0];
            __syncthreads();
        }
        if (t == 0)
            astore64(myPubR, (1ULL << 56) | (((unsigned long long)TL) << 20) |
                             (unsigned long long)ipref);
    }

    // ---- all blocks: poll refine publish, then mask ----
    if (t == 0) {
        unsigned long long v;
        while (((v = aload64(myPubR)) >> 56) != 1ULL) __builtin_amdgcn_s_sleep(4);
        s_pub = v;
    }
    __syncthreads();
    unsigned long long vR = s_pub;
    unsigned int TL   = (unsigned int)((vR >> 20) & 0xFFFFFFFFULL);
    unsigned int sCut = (unsigned int)(vR & 0xFFFFFULL);

    float4* ob = (float4*)(out + (size_t)b * S);
#pragma unroll
    for (int u = 0; u < 2; ++u)
#pragma unroll
        for (int m4 = 0; m4 < 4; ++m4) {
            uint4 kv = *(const uint4*)(kb + tb[u] + 4 * m4);
            unsigned int ks[4] = {kv.x, kv.y, kv.z, kv.w};
            float ov[4];
#pragma unroll
            for (int c = 0; c < 4; ++c) {
                float v = 0.0f;
                if (ks[c] > pref) {
                    v = 1.0f;
                } else if (ks[c] == pref) {
                    int s = tb[u] + 4 * m4 + c;
                    unsigned int low = (unsigned int)d2key(Wb[s]);
                    v = (low > TL || (low == TL && (unsigned int)s >= sCut)) ? 1.0f : 0.0f;
                }
                ov[c] = v;
            }
            ob[(tb[u] >> 2) + m4] = make_float4(ov[0], ov[1], ov[2], ov[3]);
        }
}

// ---------------------------------------------------------------------------
extern "C" void kernel_launch(void* const* d_in, const int* in_sizes, int n_in,
                              void* d_out, int out_size, void* d_ws, size_t ws_size,
                              hipStream_t stream) {
    const float* x = (const float*)d_in[0];
    float* out = (float*)d_out;

    char* ws = (char*)d_ws;
    size_t off = 0;
    auto alloc = [&](size_t bytes) -> void* {
        void* p = ws + off;
        off += (bytes + 255) & ~(size_t)255;
        return p;
    };

    double* E     = (double*)alloc((size_t)BB * S * sizeof(double));       // 16 MB
    double* Ch    = (double*)alloc((size_t)BB * S * sizeof(double));       // 16 MB
    double* Cc    = (double*)alloc((size_t)BB * S * sizeof(double));       // 16 MB
    double* L     = (double*)alloc((size_t)BB * S * sizeof(double));       // 16 MB
    unsigned int* key32 = (unsigned int*)alloc((size_t)BB * S * sizeof(unsigned int)); // 8 MB
    double* W     = E;  // E dead after gemm_nt -> reuse for weighted
    unsigned int* bar   = (unsigned int*)alloc(2048);
    unsigned int* ghist = (unsigned int*)alloc(4 * 2 * 16 * 256 * sizeof(unsigned int)); // 128 KB
    unsigned int* eqcnt = (unsigned int*)alloc(BB * 64);
    unsigned long long* cand =
        (unsigned long long*)alloc((size_t)BB * EQCAP * sizeof(unsigned long long));     // 2 MB
    unsigned long long* pubA = (unsigned long long*)alloc(128);
    unsigned long long* pubR = (unsigned long long*)alloc(128);

    // 1) pairwise adjacencies (fused per-row stats)
    k_pairwise<<<dim3(N / 64, N / 64, BB), 256, 0, stream>>>(x, E, Ch, Cc);

    // 2) logits = (E @ Ch^T) * 1/8
    k_gemm_nt<<<dim3(N / 64, N / 64, BB), 256, 0, stream>>>(E, Ch, L, 0.125);

    // 3) softmax rows
    k_softmax<<<512, 256, 0, stream>>>(L);

    // 4) weighted = attn @ Cc + key32 epilogue (+ zeroes select scratch)
    k_gemm_nn<<<dim3(N / 64, N / 64, BB), 256, 0, stream>>>(L, Cc, W, key32, bar,
                                                            ghist, eqcnt, pubA, pubR);

    // 5) fused selection (5 barriers, leader-scan publish, XCD-aligned tiles)
    k_select<<<NSELBLK, 256, 0, stream>>>(key32, W, ghist, eqcnt, cand, pubA, pubR, bar, out);
}